// Round 13
// baseline (192.346 us; speedup 1.0000x reference)
//
#include <hip/hip_runtime.h>

typedef _Float16 f16;
typedef _Float16 f16x4 __attribute__((ext_vector_type(4)));
typedef _Float16 f16x8 __attribute__((ext_vector_type(8)));
typedef float f32x4v __attribute__((ext_vector_type(4)));

#define AS1 __attribute__((address_space(1)))
#define AS3 __attribute__((address_space(3)))

// async global->LDS, 16B per lane; LDS dest = wave-uniform base + lane*16
__device__ __forceinline__ void gload_lds16(const f16* g, f16* l) {
  __builtin_amdgcn_global_load_lds((const AS1 unsigned int*)g,
                                   (AS3 unsigned int*)l, 16, 0, 0);
}

// ---------------------------------------------------------------------------
// prep: fp32 -> fp16, grid-stride (G11), 8 elems per thread-iter.
// ---------------------------------------------------------------------------
__global__ __launch_bounds__(256) void prep_kernel(
    const float* __restrict__ Q_seq, const float* __restrict__ K_seq,
    const float* __restrict__ V_seq,
    const float* __restrict__ Wq, const float* __restrict__ Wk,
    const float* __restrict__ Wv,
    f16* __restrict__ Qb, f16* __restrict__ Kb, f16* __restrict__ Vb,
    f16* __restrict__ Wqb, f16* __restrict__ Wkb, f16* __restrict__ Wvb)
{
  for (long long g = (long long)blockIdx.x * 256 + threadIdx.x;
       g < 5111808; g += (long long)2048 * 256) {
    const float* s;
    f16* d;
    if (g < 524288) {
      s = Q_seq + g * 8; d = Qb + g * 8;
    } else if (g < 2621440) {
      long long e = (g - 524288) * 8; s = K_seq + e; d = Kb + e;
    } else if (g < 4718592) {
      long long e = (g - 2621440) * 8; s = V_seq + e; d = Vb + e;
    } else if (g < 4849664) {
      long long e = (g - 4718592) * 8; s = Wq + e; d = Wqb + e;
    } else if (g < 4980736) {
      long long e = (g - 4849664) * 8; s = Wk + e; d = Wkb + e;
    } else {
      long long e = (g - 4980736) * 8; s = Wv + e; d = Wvb + e;
    }
    float4 v0 = *(const float4*)s;
    float4 v1 = *(const float4*)(s + 4);
    f16x8 o;
    o[0] = (f16)v0.x; o[1] = (f16)v0.y; o[2] = (f16)v0.z; o[3] = (f16)v0.w;
    o[4] = (f16)v1.x; o[5] = (f16)v1.y; o[6] = (f16)v1.z; o[7] = (f16)v1.w;
    *(f16x8*)d = o;
  }
}

// ---------------------------------------------------------------------------
// 128x128 tile GEMM, BK=64, 4 waves (2x2), SINGLE-buffered 32 KB LDS,
// plain 2-barrier loop (m97 structure). Occupancy is the mechanism:
// 4 blocks/CU overlap each other's stage/barrier phases (m114).
// LDS layout: A[128][64] at 0, B[128][64] at 8192 (f16 units, row stride 64).
// Staging instr s covers rows s*32 + (t>>3): 32 rows = 2048 f16 per instr
// (dest = sbuf + s*2048 + w*512, wave-uniform; HW adds lane*16B).
// T2: granule XOR swizzle phys = log ^ (row&7) via pre-swizzled global
// source (linear LDS dest); reads apply matching XOR -> 2-way (free).
// ---------------------------------------------------------------------------
__device__ __forceinline__ void gemm_tile_128(
    const f16* __restrict__ A, const f16* __restrict__ W,
    const float* __restrict__ bias, f16* __restrict__ C,
    int m0, int n0, int rowShift, int outStride, int rowOff,
    f16* sbuf)
{
  const int t = threadIdx.x;
  const int w = t >> 6, lane = t & 63;
  const int wr = w >> 1, wc = w & 1;        // 2 x 2 wave grid
  const int fr = lane & 15, g = lane >> 4;  // fragment row / k-group
  const int kgr = (t & 7) ^ ((t >> 3) & 7); // staging pre-swizzled granule

  // staging: instr s covers rows s*32 + (t>>3); 4 instrs for A, 4 for B
  const f16* aS = A + (long long)(m0 + (t >> 3)) * 1024 + kgr * 8;
  const f16* bS = W + (long long)(n0 + (t >> 3)) * 1024 + kgr * 8;
  f16* lA = sbuf + w * 512;           // + s*2048 ; HW adds lane*16B
  f16* lB = sbuf + 8192 + w * 512;

  // fragment read offsets (f16 units), granule XOR-swizzled
  const int gk0 = ((0 + g) ^ (fr & 7)) * 8;   // k-half 0
  const int gk1 = ((4 + g) ^ (fr & 7)) * 8;   // k-half 1
  const int aoff = (wr * 64 + fr) * 64;
  const int boff = (wc * 64 + fr) * 64;

  f32x4v acc[4][4];
#pragma unroll
  for (int i = 0; i < 4; ++i)
#pragma unroll
    for (int j = 0; j < 4; ++j) acc[i][j] = (f32x4v){0.f, 0.f, 0.f, 0.f};

  for (int tt = 0; tt < 16; ++tt) {
    const int ko = tt * 64;
#pragma unroll
    for (int s = 0; s < 4; ++s)
      gload_lds16(aS + s * 32768 + ko, lA + s * 2048);
#pragma unroll
    for (int s = 0; s < 4; ++s)
      gload_lds16(bS + s * 32768 + ko, lB + s * 2048);
    __syncthreads();   // drains vmcnt: tile resident for all waves

    f16x8 af[4], bf[4];
#pragma unroll
    for (int i = 0; i < 4; ++i)
      af[i] = *(const f16x8*)(sbuf + aoff + i * 1024 + gk0);
#pragma unroll
    for (int j = 0; j < 4; ++j)
      bf[j] = *(const f16x8*)(sbuf + 8192 + boff + j * 1024 + gk0);
#pragma unroll
    for (int i = 0; i < 4; ++i)
#pragma unroll
      for (int j = 0; j < 4; ++j)
        acc[i][j] = __builtin_amdgcn_mfma_f32_16x16x32_f16(af[i], bf[j],
                                                           acc[i][j], 0, 0, 0);
#pragma unroll
    for (int i = 0; i < 4; ++i)
      af[i] = *(const f16x8*)(sbuf + aoff + i * 1024 + gk1);
#pragma unroll
    for (int j = 0; j < 4; ++j)
      bf[j] = *(const f16x8*)(sbuf + 8192 + boff + j * 1024 + gk1);
#pragma unroll
    for (int i = 0; i < 4; ++i)
#pragma unroll
      for (int j = 0; j < 4; ++j)
        acc[i][j] = __builtin_amdgcn_mfma_f32_16x16x32_f16(af[i], bf[j],
                                                           acc[i][j], 0, 0, 0);

    __syncthreads();   // all reads done before next stage overwrites
  }

  // ---- epilogue: acc -> Cs[128][136] (XOR-swizzled) -> coalesced stores ----
  f16* Cs = sbuf;
  float bn[4];
#pragma unroll
  for (int j = 0; j < 4; ++j) bn[j] = bias[n0 + wc * 64 + j * 16 + fr];
#pragma unroll
  for (int i = 0; i < 4; ++i) {
#pragma unroll
    for (int j = 0; j < 4; ++j) {
#pragma unroll
      for (int v = 0; v < 4; ++v) {
        // C/D layout: col = lane&15, row = (lane>>4)*4 + v
        int row = wr * 64 + i * 16 + g * 4 + v;
        int col = wc * 64 + j * 16 + fr;
        Cs[row * 136 + (col ^ ((row & 12) << 2))] = (f16)(acc[i][j][v] + bn[j]);
      }
    }
  }
  __syncthreads();

  const int rowMask = (1 << rowShift) - 1;
  const int row = t >> 1, half = t & 1;
  const int rsw = (row & 12) << 2;
  const int arow = m0 + row;
  const int orow = (arow >> rowShift) * outStride + (arow & rowMask) + rowOff;
  f16* dst = C + (long long)orow * 1024 + n0 + half * 64;
  const f16* srcr = Cs + row * 136;
#pragma unroll
  for (int c = 0; c < 8; ++c)
    *(f16x8*)(dst + c * 8) = *(const f16x8*)(srcr + ((half * 64 + c * 8) ^ rsw));
}

// ---------------------------------------------------------------------------
// All five projection GEMMs, ONE launch, 2816 blocks = 8 * 352 (bijective
// XCD swizzle; n-tile fastest within a chunk -> A panel L2-resident).
// v < 2048: K/V body (M=16384, 128 m-tiles x 8 n-tiles each);
// v >= 2048: Q-side (M=4096): z=0 Qh, z=1 Kh title rows, z=2 Vh title rows.
// ---------------------------------------------------------------------------
__global__ __launch_bounds__(256) void gemm_all(
    const f16* __restrict__ Qb, const f16* __restrict__ Kb,
    const f16* __restrict__ Vb,
    const f16* __restrict__ Wqb, const f16* __restrict__ Wkb,
    const f16* __restrict__ Wvb,
    const float* __restrict__ bq, const float* __restrict__ bk,
    const float* __restrict__ bv,
    f16* __restrict__ Qh, f16* __restrict__ Kh, f16* __restrict__ Vh)
{
  __shared__ __align__(16) f16 sbuf[17408];   // 34816 B (staging 32 KB + Cs)
  const int bid = blockIdx.x;
  const int v = (bid & 7) * 352 + (bid >> 3);

  const f16* A;
  const f16* W;
  const float* bias;
  f16* C;
  int m0, n0, rowShift, outStride, rowOff;

  if (v < 2048) {
    const int z = v >> 10, rem = v & 1023;
    A = z ? Vb : Kb;
    W = z ? Wvb : Wkb;
    bias = z ? bv : bk;
    C = z ? Vh : Kh;
    m0 = (rem >> 3) * 128; n0 = (rem & 7) * 128;
    rowShift = 7; outStride = 160; rowOff = 0;
  } else {
    const int u = v - 2048;
    const int z = u >> 8, rem = u & 255;
    A = Qb;
    W = (z == 0) ? Wqb : (z == 1) ? Wkb : Wvb;
    bias = (z == 0) ? bq : (z == 1) ? bk : bv;
    C = (z == 0) ? Qh : (z == 1) ? Kh : Vh;
    m0 = (rem >> 3) * 128; n0 = (rem & 7) * 128;
    rowShift = 5;
    outStride = (z == 0) ? 32 : 160;
    rowOff = (z == 0) ? 0 : 128;
  }
  gemm_tile_128(A, W, bias, C, m0, n0, rowShift, outStride, rowOff, sbuf);
}

// ---------------------------------------------------------------------------
// MFMA attention: one block per (b,h), 4 waves. (unchanged)
// ---------------------------------------------------------------------------
__global__ __launch_bounds__(256) void attn_kernel(
    const f16* __restrict__ Qh, const f16* __restrict__ Kh,
    const f16* __restrict__ Vh,
    const float* __restrict__ title, const float* __restrict__ body,
    float* __restrict__ out)
{
  __shared__ __align__(16) f16 Qs[32 * 72];    // stride 144B (b128-friendly)
  __shared__ __align__(16) f16 Ks[160 * 72];   // reused as Ps[32][168] (336B)
  __shared__ __align__(16) f16 Vs[160 * 68];   // stride 136B (2-way max on u16)
  __shared__ float rs[4][32];
  __shared__ float invs[32];

  const int bh = blockIdx.x, b = bh >> 4, h = bh & 15;
  const int t = threadIdx.x, w = t >> 6, lane = t & 63;
  const int c = lane & 15, g = lane >> 4;

  const long long qbase = ((long long)(b * 32) << 10) + h * 64;
  const long long kbase = ((long long)(b * 160) << 10) + h * 64;

  {
    int row = t >> 3, ch = t & 7;
    *(f16x8*)(Qs + row * 72 + ch * 8) =
        *(const f16x8*)(Qh + qbase + (long long)row * 1024 + ch * 8);
  }
#pragma unroll
  for (int r = 0; r < 5; ++r) {
    int i = t + r * 256;
    int row = i >> 3, ch = i & 7;
    *(f16x8*)(Ks + row * 72 + ch * 8) =
        *(const f16x8*)(Kh + kbase + (long long)row * 1024 + ch * 8);
    f16x8 vv = *(const f16x8*)(Vh + kbase + (long long)row * 1024 + ch * 8);
    f16x4 vlo = __builtin_shufflevector(vv, vv, 0, 1, 2, 3);
    f16x4 vhi = __builtin_shufflevector(vv, vv, 4, 5, 6, 7);
    *(f16x4*)(Vs + row * 68 + ch * 8) = vlo;
    *(f16x4*)(Vs + row * 68 + ch * 8 + 4) = vhi;
  }
  __syncthreads();

  f16x8 qf[2][2];
#pragma unroll
  for (int qt = 0; qt < 2; ++qt)
#pragma unroll
    for (int s = 0; s < 2; ++s)
      qf[qt][s] = *(const f16x8*)(Qs + (qt * 16 + c) * 72 + s * 32 + g * 8);

  const int cnt = (w < 2) ? 3 : 2;
  const int tile0 = (w < 2) ? w * 3 : 6 + (w - 2) * 2;

  f16x4 pp[3][2];
  float rsum[2] = {0.f, 0.f};

#pragma unroll
  for (int i = 0; i < 3; ++i) {
    if (i < cnt) {
      const int kt = tile0 + i;
      f16x8 kf0 = *(const f16x8*)(Ks + (kt * 16 + c) * 72 + 0 + g * 8);
      f16x8 kf1 = *(const f16x8*)(Ks + (kt * 16 + c) * 72 + 32 + g * 8);
#pragma unroll
      for (int qt = 0; qt < 2; ++qt) {
        f32x4v s4 = (f32x4v){0.f, 0.f, 0.f, 0.f};
        s4 = __builtin_amdgcn_mfma_f32_16x16x32_f16(kf0, qf[qt][0], s4, 0, 0, 0);
        s4 = __builtin_amdgcn_mfma_f32_16x16x32_f16(kf1, qf[qt][1], s4, 0, 0, 0);
        float4 m4;
        if (kt < 8) {
          m4 = *(const float4*)(body +
                ((long long)(b * 32 + qt * 16 + c)) * 128 + kt * 16 + 4 * g);
        } else {
          m4 = *(const float4*)(title + b * 32 + (kt - 8) * 16 + 4 * g);
        }
        float e0 = __expf(s4[0] * 0.125f) * m4.x;
        float e1 = __expf(s4[1] * 0.125f) * m4.y;
        float e2 = __expf(s4[2] * 0.125f) * m4.z;
        float e3 = __expf(s4[3] * 0.125f) * m4.w;
        rsum[qt] += (e0 + e1) + (e2 + e3);
        f16x4 p4;
        p4.x = (f16)e0; p4.y = (f16)e1; p4.z = (f16)e2; p4.w = (f16)e3;
        pp[i][qt] = p4;
      }
    }
  }

#pragma unroll
  for (int qt = 0; qt < 2; ++qt) {
    rsum[qt] += __shfl_xor(rsum[qt], 16);
    rsum[qt] += __shfl_xor(rsum[qt], 32);
  }
  if (lane < 16) {
    rs[w][c] = rsum[0];
    rs[w][16 + c] = rsum[1];
  }
  __syncthreads();

  f16* Ps = Ks;
#pragma unroll
  for (int i = 0; i < 3; ++i) {
    if (i < cnt) {
      const int kt = tile0 + i;
#pragma unroll
      for (int qt = 0; qt < 2; ++qt)
        *(f16x4*)(Ps + (qt * 16 + c) * 168 + kt * 16 + 4 * g) = pp[i][qt];
    }
  }
  if (t < 32) {
    float ssum = rs[0][t] + rs[1][t] + rs[2][t] + rs[3][t];
    invs[t] = title[b * 32 + t] / (ssum + 1e-8f);
  }
  __syncthreads();

  f32x4v o[2] = {(f32x4v){0.f, 0.f, 0.f, 0.f}, (f32x4v){0.f, 0.f, 0.f, 0.f}};
#pragma unroll
  for (int s = 0; s < 5; ++s) {
    f16x8 vf;
#pragma unroll
    for (int j = 0; j < 8; ++j)
      vf[j] = Vs[(32 * s + 8 * g + j) * 68 + 16 * w + c];
#pragma unroll
    for (int qt = 0; qt < 2; ++qt) {
      f16x8 pf = *(const f16x8*)(Ps + (qt * 16 + c) * 168 + s * 32 + g * 8);
      o[qt] = __builtin_amdgcn_mfma_f32_16x16x32_f16(pf, vf, o[qt], 0, 0, 0);
    }
  }

#pragma unroll
  for (int qt = 0; qt < 2; ++qt) {
#pragma unroll
    for (int v = 0; v < 4; ++v) {
      int q = qt * 16 + 4 * g + v;
      out[((long long)(b * 32 + q) << 10) + h * 64 + 16 * w + c] =
          o[qt][v] * invs[q];
    }
  }
}

// ---------------------------------------------------------------------------
extern "C" void kernel_launch(void* const* d_in, const int* in_sizes, int n_in,
                              void* d_out, int out_size, void* d_ws, size_t ws_size,
                              hipStream_t stream) {
  const float* Q_seq = (const float*)d_in[0];
  const float* K_seq = (const float*)d_in[1];
  const float* V_seq = (const float*)d_in[2];
  const float* title = (const float*)d_in[3];
  const float* body  = (const float*)d_in[4];
  const float* Wq = (const float*)d_in[5];
  const float* bq = (const float*)d_in[6];
  const float* Wk = (const float*)d_in[7];
  const float* bk = (const float*)d_in[8];
  const float* Wv = (const float*)d_in[9];
  const float* bv = (const float*)d_in[10];
  float* out = (float*)d_out;

  f16* ws = (f16*)d_ws;
  f16* Qb  = ws;
  f16* Kb  = Qb + 4194304;
  f16* Vb  = Kb + 16777216;
  f16* Wqb = Vb + 16777216;
  f16* Wkb = Wqb + 1048576;
  f16* Wvb = Wkb + 1048576;
  f16* Qh  = Wvb + 1048576;
  f16* Kh  = Qh + 4194304;
  f16* Vh  = Kh + 20971520;

  prep_kernel<<<2048, 256, 0, stream>>>(Q_seq, K_seq, V_seq, Wq, Wk, Wv,
                                        Qb, Kb, Vb, Wqb, Wkb, Wvb);
  gemm_all<<<2816, 256, 0, stream>>>(Qb, Kb, Vb, Wqb, Wkb, Wvb,
                                     bq, bk, bv, Qh, Kh, Vh);
  attn_kernel<<<2048, 256, 0, stream>>>(Qh, Kh, Vh, title, body, out);
}

// Round 14
// 174.395 us; speedup vs baseline: 1.1029x; 1.1029x over previous
//
#include <hip/hip_runtime.h>

typedef _Float16 f16;
typedef _Float16 f16x4 __attribute__((ext_vector_type(4)));
typedef _Float16 f16x8 __attribute__((ext_vector_type(8)));
typedef float f32x4v __attribute__((ext_vector_type(4)));

#define AS1 __attribute__((address_space(1)))
#define AS3 __attribute__((address_space(3)))

// async global->LDS, 16B per lane; LDS dest = wave-uniform base + lane*16
__device__ __forceinline__ void gload_lds16(const f16* g, f16* l) {
  __builtin_amdgcn_global_load_lds((const AS1 unsigned int*)g,
                                   (AS3 unsigned int*)l, 16, 0, 0);
}

// ---------------------------------------------------------------------------
// prep_w: weights only, fp32 -> fp16 (3 x 1M elems, ~12 MB). ~3 us.
// ---------------------------------------------------------------------------
__global__ __launch_bounds__(256) void prep_w(
    const float* __restrict__ Wq, const float* __restrict__ Wk,
    const float* __restrict__ Wv,
    f16* __restrict__ Wqb, f16* __restrict__ Wkb, f16* __restrict__ Wvb)
{
  const long long g = (long long)blockIdx.x * 256 + threadIdx.x;  // < 393216
  const float* s;
  f16* d;
  if (g < 131072) {
    s = Wq + g * 8; d = Wqb + g * 8;
  } else if (g < 262144) {
    long long e = (g - 131072) * 8; s = Wk + e; d = Wkb + e;
  } else {
    long long e = (g - 262144) * 8; s = Wv + e; d = Wvb + e;
  }
  float4 v0 = *(const float4*)s;
  float4 v1 = *(const float4*)(s + 4);
  f16x8 o;
  o[0] = (f16)v0.x; o[1] = (f16)v0.y; o[2] = (f16)v0.z; o[3] = (f16)v0.w;
  o[4] = (f16)v1.x; o[5] = (f16)v1.y; o[6] = (f16)v1.z; o[7] = (f16)v1.w;
  *(f16x8*)d = o;
}

// ---------------------------------------------------------------------------
// 128x128 tile GEMM with FUSED fp32 A input. BK=64, 4 waves (2x2),
// single-buffered LDS: A f32[128][64] (32 KB) + B f16[128][64] (16 KB).
// A staged fp32 via gload_lds DMA (no reg-staging - r10 lesson); A fragments
// converted to f16 in-register after ds_read (VALU pipe is half-idle).
// A swizzle (16B granules, 16/row): phys16 = log16 ^ (row&15); staging keeps
// LDS dest linear and pre-swizzles the GLOBAL source col; reads apply the
// matching XOR. Read spread: 8 dword-accesses/bank = the 1KB/wave floor.
// B path identical to round-13 (verified): 8 granules/row, phys = log^(row&7).
// ---------------------------------------------------------------------------
__device__ __forceinline__ void gemm_tile_128_f32A(
    const float* __restrict__ A, const f16* __restrict__ W,
    const float* __restrict__ bias, f16* __restrict__ C,
    int m0, int n0, int rowShift, int outStride, int rowOff,
    f16* sbuf)
{
  const int t = threadIdx.x;
  const int w = t >> 6, lane = t & 63;
  const int wr = w >> 1, wc = w & 1;        // 2 x 2 wave grid
  const int fr = lane & 15, g = lane >> 4;  // fragment row / k-group

  // ---- A staging: 32 units of 1KB; unit u = s*4+w covers rows u*4..u*4+4.
  // lane: row-in-unit = lane>>4, granule16 = lane&15; src granule = ^(row&15)
  const int arow4 = lane >> 4;                       // 0..3
  const int ax = w * 4 + arow4;                      // row&15 (s*16 drops out)
  const float* aSrc = A + (long long)(m0 + ax) * 1024 + ((lane & 15) ^ ax) * 4;

  // ---- B staging: 16 units of 1KB; unit = s*4+w covers rows unit*8..+8.
  const int brow = lane >> 3;                        // 0..7 (= row&7)
  const f16* bSrc = W + (long long)(n0 + w * 8 + brow) * 1024 +
                    ((lane & 7) ^ brow) * 8;

  const float* Asl = (const float*)sbuf;   // f32[128][64]
  const f16* Bsl = sbuf + 16384;           // f16[128][64] (bytes 32768..49152)

  const int aoff = (wr * 64 + fr) * 64;    // f32 units
  const int boff = (wc * 64 + fr) * 64;    // f16 units
  const int gkB0 = ((0 + g) ^ (fr & 7)) * 8;   // B granule16 offsets (f16)
  const int gkB1 = ((4 + g) ^ (fr & 7)) * 8;
  const int pa0 = ((2 * g) ^ fr) * 4;          // A phys16 (f32 units), kh0
  const int pa1 = ((2 * (4 + g)) ^ fr) * 4;    // kh1

  f32x4v acc[4][4];
#pragma unroll
  for (int i = 0; i < 4; ++i)
#pragma unroll
    for (int j = 0; j < 4; ++j) acc[i][j] = (f32x4v){0.f, 0.f, 0.f, 0.f};

#define CVT8(dst, p)                                                         \
  {                                                                          \
    float4 q0_ = *(const float4*)(p);                                        \
    float4 q1_ = *(const float4*)((p) + ((pa_sw) ? -4 : 4));                 \
    dst[0] = (f16)q0_.x; dst[1] = (f16)q0_.y;                                \
    dst[2] = (f16)q0_.z; dst[3] = (f16)q0_.w;                                \
    dst[4] = (f16)q1_.x; dst[5] = (f16)q1_.y;                                \
    dst[6] = (f16)q1_.z; dst[7] = (f16)q1_.w;                                \
  }
  // phys16 of logical half1 = half0 ^ 1 -> +16B if fr even, -16B if fr odd
  const bool pa_sw = (fr & 1);

  for (int tt = 0; tt < 16; ++tt) {
    const int ko = tt * 64;
    // stage A (8 instrs) + B (4 instrs); dest linear, source pre-swizzled
#pragma unroll
    for (int s = 0; s < 8; ++s)
      gload_lds16((const f16*)(aSrc + (long long)s * 16 * 1024 + ko),
                  sbuf + (s * 4 + w) * 512);
#pragma unroll
    for (int s = 0; s < 4; ++s)
      gload_lds16(bSrc + (long long)s * 32 * 1024 + ko,
                  sbuf + 16384 + (s * 4 + w) * 512);
    __syncthreads();   // drains vmcnt: tile resident for all waves

    f16x8 af[4], bf[4];
    // ---- k-half 0 ----
#pragma unroll
    for (int i = 0; i < 4; ++i) {
      const float* p = Asl + aoff + i * 1024 + pa0;
      CVT8(af[i], p);
    }
#pragma unroll
    for (int j = 0; j < 4; ++j)
      bf[j] = *(const f16x8*)(Bsl + boff + j * 1024 + gkB0);
#pragma unroll
    for (int i = 0; i < 4; ++i)
#pragma unroll
      for (int j = 0; j < 4; ++j)
        acc[i][j] = __builtin_amdgcn_mfma_f32_16x16x32_f16(af[i], bf[j],
                                                           acc[i][j], 0, 0, 0);
    // ---- k-half 1 ----
#pragma unroll
    for (int i = 0; i < 4; ++i) {
      const float* p = Asl + aoff + i * 1024 + pa1;
      CVT8(af[i], p);
    }
#pragma unroll
    for (int j = 0; j < 4; ++j)
      bf[j] = *(const f16x8*)(Bsl + boff + j * 1024 + gkB1);
#pragma unroll
    for (int i = 0; i < 4; ++i)
#pragma unroll
      for (int j = 0; j < 4; ++j)
        acc[i][j] = __builtin_amdgcn_mfma_f32_16x16x32_f16(af[i], bf[j],
                                                           acc[i][j], 0, 0, 0);

    __syncthreads();   // all reads done before next stage overwrites
  }
#undef CVT8

  // pa_sw read fix: if fr odd, q0_ read phys of logical half1. Swap halves.
  // (handled below by loading with explicit addresses instead)

  // ---- epilogue: acc -> Cs[128][136] (XOR-swizzled) -> coalesced stores ----
  f16* Cs = sbuf;
  float bn[4];
#pragma unroll
  for (int j = 0; j < 4; ++j) bn[j] = bias[n0 + wc * 64 + j * 16 + fr];
#pragma unroll
  for (int i = 0; i < 4; ++i) {
#pragma unroll
    for (int j = 0; j < 4; ++j) {
#pragma unroll
      for (int v = 0; v < 4; ++v) {
        // C/D layout: col = lane&15, row = (lane>>4)*4 + v
        int row = wr * 64 + i * 16 + g * 4 + v;
        int col = wc * 64 + j * 16 + fr;
        Cs[row * 136 + (col ^ ((row & 12) << 2))] = (f16)(acc[i][j][v] + bn[j]);
      }
    }
  }
  __syncthreads();

  const int rowMask = (1 << rowShift) - 1;
  const int row = t >> 1, half = t & 1;
  const int rsw = (row & 12) << 2;
  const int arow = m0 + row;
  const int orow = (arow >> rowShift) * outStride + (arow & rowMask) + rowOff;
  f16* dst = C + (long long)orow * 1024 + n0 + half * 64;
  const f16* srcr = Cs + row * 136;
#pragma unroll
  for (int c = 0; c < 8; ++c)
    *(f16x8*)(dst + c * 8) = *(const f16x8*)(srcr + ((half * 64 + c * 8) ^ rsw));
}

// ---------------------------------------------------------------------------
// All five projection GEMMs, ONE launch, 2816 blocks = 8 * 352 (bijective
// XCD swizzle; n-tile fastest). A inputs are fp32 (Q_seq/K_seq/V_seq),
// weights fp16. v<2048: K/V body; v>=2048: Q-side (z=0 Qh, 1 Kh-title,
// 2 Vh-title).
// ---------------------------------------------------------------------------
__global__ __launch_bounds__(256) void gemm_all(
    const float* __restrict__ Q_seq, const float* __restrict__ K_seq,
    const float* __restrict__ V_seq,
    const f16* __restrict__ Wqb, const f16* __restrict__ Wkb,
    const f16* __restrict__ Wvb,
    const float* __restrict__ bq, const float* __restrict__ bk,
    const float* __restrict__ bv,
    f16* __restrict__ Qh, f16* __restrict__ Kh, f16* __restrict__ Vh)
{
  __shared__ __align__(16) f16 sbuf[24576];   // 49152 B: A f32 32K + B f16 16K
  const int bid = blockIdx.x;
  const int v = (bid & 7) * 352 + (bid >> 3);

  const float* A;
  const f16* W;
  const float* bias;
  f16* C;
  int m0, n0, rowShift, outStride, rowOff;

  if (v < 2048) {
    const int z = v >> 10, rem = v & 1023;
    A = z ? V_seq : K_seq;
    W = z ? Wvb : Wkb;
    bias = z ? bv : bk;
    C = z ? Vh : Kh;
    m0 = (rem >> 3) * 128; n0 = (rem & 7) * 128;
    rowShift = 7; outStride = 160; rowOff = 0;
  } else {
    const int u = v - 2048;
    const int z = u >> 8, rem = u & 255;
    A = Q_seq;
    W = (z == 0) ? Wqb : (z == 1) ? Wkb : Wvb;
    bias = (z == 0) ? bq : (z == 1) ? bk : bv;
    C = (z == 0) ? Qh : (z == 1) ? Kh : Vh;
    m0 = (rem >> 3) * 128; n0 = (rem & 7) * 128;
    rowShift = 5;
    outStride = (z == 0) ? 32 : 160;
    rowOff = (z == 0) ? 0 : 128;
  }
  gemm_tile_128_f32A(A, W, bias, C, m0, n0, rowShift, outStride, rowOff, sbuf);
}

// ---------------------------------------------------------------------------
// MFMA attention: one block per (b,h), 4 waves. (unchanged)
// ---------------------------------------------------------------------------
__global__ __launch_bounds__(256) void attn_kernel(
    const f16* __restrict__ Qh, const f16* __restrict__ Kh,
    const f16* __restrict__ Vh,
    const float* __restrict__ title, const float* __restrict__ body,
    float* __restrict__ out)
{
  __shared__ __align__(16) f16 Qs[32 * 72];    // stride 144B (b128-friendly)
  __shared__ __align__(16) f16 Ks[160 * 72];   // reused as Ps[32][168] (336B)
  __shared__ __align__(16) f16 Vs[160 * 68];   // stride 136B (2-way max on u16)
  __shared__ float rs[4][32];
  __shared__ float invs[32];

  const int bh = blockIdx.x, b = bh >> 4, h = bh & 15;
  const int t = threadIdx.x, w = t >> 6, lane = t & 63;
  const int c = lane & 15, g = lane >> 4;

  const long long qbase = ((long long)(b * 32) << 10) + h * 64;
  const long long kbase = ((long long)(b * 160) << 10) + h * 64;

  {
    int row = t >> 3, ch = t & 7;
    *(f16x8*)(Qs + row * 72 + ch * 8) =
        *(const f16x8*)(Qh + qbase + (long long)row * 1024 + ch * 8);
  }
#pragma unroll
  for (int r = 0; r < 5; ++r) {
    int i = t + r * 256;
    int row = i >> 3, ch = i & 7;
    *(f16x8*)(Ks + row * 72 + ch * 8) =
        *(const f16x8*)(Kh + kbase + (long long)row * 1024 + ch * 8);
    f16x8 vv = *(const f16x8*)(Vh + kbase + (long long)row * 1024 + ch * 8);
    f16x4 vlo = __builtin_shufflevector(vv, vv, 0, 1, 2, 3);
    f16x4 vhi = __builtin_shufflevector(vv, vv, 4, 5, 6, 7);
    *(f16x4*)(Vs + row * 68 + ch * 8) = vlo;
    *(f16x4*)(Vs + row * 68 + ch * 8 + 4) = vhi;
  }
  __syncthreads();

  f16x8 qf[2][2];
#pragma unroll
  for (int qt = 0; qt < 2; ++qt)
#pragma unroll
    for (int s = 0; s < 2; ++s)
      qf[qt][s] = *(const f16x8*)(Qs + (qt * 16 + c) * 72 + s * 32 + g * 8);

  const int cnt = (w < 2) ? 3 : 2;
  const int tile0 = (w < 2) ? w * 3 : 6 + (w - 2) * 2;

  f16x4 pp[3][2];
  float rsum[2] = {0.f, 0.f};

#pragma unroll
  for (int i = 0; i < 3; ++i) {
    if (i < cnt) {
      const int kt = tile0 + i;
      f16x8 kf0 = *(const f16x8*)(Ks + (kt * 16 + c) * 72 + 0 + g * 8);
      f16x8 kf1 = *(const f16x8*)(Ks + (kt * 16 + c) * 72 + 32 + g * 8);
#pragma unroll
      for (int qt = 0; qt < 2; ++qt) {
        f32x4v s4 = (f32x4v){0.f, 0.f, 0.f, 0.f};
        s4 = __builtin_amdgcn_mfma_f32_16x16x32_f16(kf0, qf[qt][0], s4, 0, 0, 0);
        s4 = __builtin_amdgcn_mfma_f32_16x16x32_f16(kf1, qf[qt][1], s4, 0, 0, 0);
        float4 m4;
        if (kt < 8) {
          m4 = *(const float4*)(body +
                ((long long)(b * 32 + qt * 16 + c)) * 128 + kt * 16 + 4 * g);
        } else {
          m4 = *(const float4*)(title + b * 32 + (kt - 8) * 16 + 4 * g);
        }
        float e0 = __expf(s4[0] * 0.125f) * m4.x;
        float e1 = __expf(s4[1] * 0.125f) * m4.y;
        float e2 = __expf(s4[2] * 0.125f) * m4.z;
        float e3 = __expf(s4[3] * 0.125f) * m4.w;
        rsum[qt] += (e0 + e1) + (e2 + e3);
        f16x4 p4;
        p4.x = (f16)e0; p4.y = (f16)e1; p4.z = (f16)e2; p4.w = (f16)e3;
        pp[i][qt] = p4;
      }
    }
  }

#pragma unroll
  for (int qt = 0; qt < 2; ++qt) {
    rsum[qt] += __shfl_xor(rsum[qt], 16);
    rsum[qt] += __shfl_xor(rsum[qt], 32);
  }
  if (lane < 16) {
    rs[w][c] = rsum[0];
    rs[w][16 + c] = rsum[1];
  }
  __syncthreads();

  f16* Ps = Ks;
#pragma unroll
  for (int i = 0; i < 3; ++i) {
    if (i < cnt) {
      const int kt = tile0 + i;
#pragma unroll
      for (int qt = 0; qt < 2; ++qt)
        *(f16x4*)(Ps + (qt * 16 + c) * 168 + kt * 16 + 4 * g) = pp[i][qt];
    }
  }
  if (t < 32) {
    float ssum = rs[0][t] + rs[1][t] + rs[2][t] + rs[3][t];
    invs[t] = title[b * 32 + t] / (ssum + 1e-8f);
  }
  __syncthreads();

  f32x4v o[2] = {(f32x4v){0.f, 0.f, 0.f, 0.f}, (f32x4v){0.f, 0.f, 0.f, 0.f}};
#pragma unroll
  for (int s = 0; s < 5; ++s) {
    f16x8 vf;
#pragma unroll
    for (int j = 0; j < 8; ++j)
      vf[j] = Vs[(32 * s + 8 * g + j) * 68 + 16 * w + c];
#pragma unroll
    for (int qt = 0; qt < 2; ++qt) {
      f16x8 pf = *(const f16x8*)(Ps + (qt * 16 + c) * 168 + s * 32 + g * 8);
      o[qt] = __builtin_amdgcn_mfma_f32_16x16x32_f16(pf, vf, o[qt], 0, 0, 0);
    }
  }

#pragma unroll
  for (int qt = 0; qt < 2; ++qt) {
#pragma unroll
    for (int v = 0; v < 4; ++v) {
      int q = qt * 16 + 4 * g + v;
      out[((long long)(b * 32 + q) << 10) + h * 64 + 16 * w + c] =
          o[qt][v] * invs[q];
    }
  }
}

// ---------------------------------------------------------------------------
extern "C" void kernel_launch(void* const* d_in, const int* in_sizes, int n_in,
                              void* d_out, int out_size, void* d_ws, size_t ws_size,
                              hipStream_t stream) {
  const float* Q_seq = (const float*)d_in[0];
  const float* K_seq = (const float*)d_in[1];
  const float* V_seq = (const float*)d_in[2];
  const float* title = (const float*)d_in[3];
  const float* body  = (const float*)d_in[4];
  const float* Wq = (const float*)d_in[5];
  const float* bq = (const float*)d_in[6];
  const float* Wk = (const float*)d_in[7];
  const float* bk = (const float*)d_in[8];
  const float* Wv = (const float*)d_in[9];
  const float* bv = (const float*)d_in[10];
  float* out = (float*)d_out;

  f16* ws = (f16*)d_ws;
  f16* Wqb = ws;
  f16* Wkb = Wqb + 1048576;
  f16* Wvb = Wkb + 1048576;
  f16* Qh  = Wvb + 1048576;       // [B*32][1024]
  f16* Kh  = Qh + 4194304;        // [B*160][1024]
  f16* Vh  = Kh + 20971520;       // [B*160][1024]

  prep_w<<<1536, 256, 0, stream>>>(Wq, Wk, Wv, Wqb, Wkb, Wvb);
  gemm_all<<<2816, 256, 0, stream>>>(Q_seq, K_seq, V_seq, Wqb, Wkb, Wvb,
                                     bq, bk, bv, Qh, Kh, Vh);
  attn_kernel<<<2048, 256, 0, stream>>>(Qh, Kh, Vh, title, body, out);
}